// Round 7
// baseline (102.489 us; speedup 1.0000x reference)
//
#include <hip/hip_runtime.h>

// PartitionPadding: out[m][p][:] = feat[starts[m]+p][:] if p < count[m] else 0.
// B=2048, MAX_ATOMS=640, D=64. Pure data movement: 256MB read + 335.5MB write.
//
// R7 = R6 (91.1us: transient-block gather + NT stores) + NT loads + fast starts.
//  - starts: thread-per-atom boundary detect (~4MB parallel reads, ~1-2us,
//    no dependent-load chains) instead of 2049-thread binary search (~5us).
//  - gather: grid (40, 2048), one NT f4 load + one NT f4 store per thread.
//    Both streams bypass cache (read-once / write-once).

#define BATCH 2048
#define MAXA  640
#define DF    64
#define ROWF4 16            // float4 per row (64 floats)

typedef float f4 __attribute__((ext_vector_type(4)));

// starts[] via parallel boundary detection on the sorted indicator.
__global__ void pp_starts_kernel(const int* __restrict__ ind, int N,
                                 int* __restrict__ starts) {
    int stride = gridDim.x * blockDim.x;
    for (int i = blockIdx.x * blockDim.x + threadIdx.x; i < N; i += stride) {
        int cur  = ind[i];
        int prev = (i == 0) ? -1 : ind[i - 1];
        if (cur != prev) {
            for (int m = prev + 1; m <= cur; ++m) starts[m] = i;
        }
        if (i == N - 1) {
            for (int m = cur + 1; m <= BATCH; ++m) starts[m] = N;
        }
    }
}

// One f4 per thread. grid = (MAXA*16/256 = 40, BATCH), block = 256.
__global__ __launch_bounds__(256) void pp_gather_kernel(
        const f4* __restrict__ feat,
        const int* __restrict__ starts,
        f4* __restrict__ out) {
    const unsigned m   = blockIdx.y;
    const unsigned idx = blockIdx.x * 256u + threadIdx.x;  // 0 .. MAXA*16-1
    const unsigned p   = idx >> 4;    // row within molecule
    const int s = starts[m];
    const int e = starts[m + 1];

    f4 v = (f4){0.f, 0.f, 0.f, 0.f};
    const int src = s + (int)p;
    if (src < e) v = __builtin_nontemporal_load(&feat[(unsigned)src * ROWF4 + (idx & 15u)]);

    __builtin_nontemporal_store(v, &out[m * (MAXA * ROWF4) + idx]);
}

extern "C" void kernel_launch(void* const* d_in, const int* in_sizes, int n_in,
                              void* d_out, int out_size, void* d_ws, size_t ws_size,
                              hipStream_t stream) {
    const float* feat = (const float*)d_in[0];
    const int*   ind  = (const int*)d_in[1];
    float*       out  = (float*)d_out;
    int*         starts = (int*)d_ws;   // BATCH+1 ints

    const int N = in_sizes[0] / DF;

    {
        int blocks = min((N + 255) / 256, 4096);
        pp_starts_kernel<<<blocks, 256, 0, stream>>>(ind, N, starts);
    }
    {
        dim3 grid(MAXA * ROWF4 / 256, BATCH);  // (40, 2048)
        pp_gather_kernel<<<grid, 256, 0, stream>>>(
            (const f4*)feat, starts, (f4*)out);
    }
}

// Round 8
// 92.313 us; speedup vs baseline: 1.1102x; 1.1102x over previous
//
#include <hip/hip_runtime.h>

// PartitionPadding: out[m][p][:] = feat[starts[m]+p][:] if p < count[m] else 0.
// B=2048, MAX_ATOMS=640, D=64. Pure data movement: 256MB read + 335.5MB write.
//
// R8 = R6 champion (91.1us: transient-block gather, CACHED loads, NT stores)
//      with ONLY the starts kernel swapped: boundary-detect scan instead of
//      per-molecule binary search (kills the 20-deep dependent-load chain).
// R7 taught: NT *loads* regress ~11us (read stream wants L2 buffering).

#define BATCH 2048
#define MAXA  640
#define DF    64
#define ROWF4 16            // float4 per row (64 floats)

typedef float f4 __attribute__((ext_vector_type(4)));

// starts[] via parallel boundary detection on the sorted indicator (~8MB
// streaming reads, no dependent chains, ~1-2us).
__global__ void pp_starts_kernel(const int* __restrict__ ind, int N,
                                 int* __restrict__ starts) {
    int stride = gridDim.x * blockDim.x;
    for (int i = blockIdx.x * blockDim.x + threadIdx.x; i < N; i += stride) {
        int cur  = ind[i];
        int prev = (i == 0) ? -1 : ind[i - 1];
        if (cur != prev) {
            for (int m = prev + 1; m <= cur; ++m) starts[m] = i;
        }
        if (i == N - 1) {
            for (int m = cur + 1; m <= BATCH; ++m) starts[m] = N;
        }
    }
}

// One f4 per thread. grid = (MAXA*16/256 = 40, BATCH), block = 256.
// Cached load (read stream benefits from L2), nontemporal store (write-once,
// keep 335MB write stream out of L2) — the R6 recipe.
__global__ __launch_bounds__(256) void pp_gather_kernel(
        const f4* __restrict__ feat,
        const int* __restrict__ starts,
        f4* __restrict__ out) {
    const unsigned m   = blockIdx.y;
    const unsigned idx = blockIdx.x * 256u + threadIdx.x;  // 0 .. MAXA*16-1
    const unsigned p   = idx >> 4;    // row within molecule
    const int s = starts[m];
    const int e = starts[m + 1];

    f4 v = (f4){0.f, 0.f, 0.f, 0.f};
    const int src = s + (int)p;
    if (src < e) v = feat[(unsigned)src * ROWF4 + (idx & 15u)];

    __builtin_nontemporal_store(v, &out[m * (MAXA * ROWF4) + idx]);
}

extern "C" void kernel_launch(void* const* d_in, const int* in_sizes, int n_in,
                              void* d_out, int out_size, void* d_ws, size_t ws_size,
                              hipStream_t stream) {
    const float* feat = (const float*)d_in[0];
    const int*   ind  = (const int*)d_in[1];
    float*       out  = (float*)d_out;
    int*         starts = (int*)d_ws;   // BATCH+1 ints

    const int N = in_sizes[0] / DF;

    {
        int blocks = min((N + 255) / 256, 4096);
        pp_starts_kernel<<<blocks, 256, 0, stream>>>(ind, N, starts);
    }
    {
        dim3 grid(MAXA * ROWF4 / 256, BATCH);  // (40, 2048)
        pp_gather_kernel<<<grid, 256, 0, stream>>>(
            (const f4*)feat, starts, (f4*)out);
    }
}